// Round 1
// baseline (3181.460 us; speedup 1.0000x reference)
//
#include <hip/hip_runtime.h>
#include <hip/hip_bf16.h>
#include <math.h>

#define BATCH 2
#define CC    256
#define NN    4096
#define KK    409          // max(1, int(0.1*4096))
#define SCALE 0.0625f      // 1/sqrt(256)

// ---------- helpers: order-preserving float<->uint key ----------
__device__ __forceinline__ unsigned fkey(float f) {
    unsigned u = __float_as_uint(f);
    return (u & 0x80000000u) ? ~u : (u | 0x80000000u);
}
__device__ __forceinline__ float keyToF(unsigned k) {
    unsigned u = (k & 0x80000000u) ? (k ^ 0x80000000u) : ~k;
    return __uint_as_float(u);
}

// ---------- kernel 1: transpose the three 256x256 weights ----------
__global__ void transpose_w(const float* __restrict__ Wq,
                            const float* __restrict__ Wk,
                            const float* __restrict__ Wv,
                            float* __restrict__ Wt) {
    int mat = blockIdx.x >> 8;        // 0..2
    int o   = blockIdx.x & 255;
    int c   = threadIdx.x;
    const float* W = (mat == 0) ? Wq : (mat == 1) ? Wk : Wv;
    // Wt[mat][c][o] = W[o][c]
    Wt[mat * 65536 + c * 256 + o] = W[o * 256 + c];
}

// ---------- kernel 2: projections Q,K,V = x^T * W^T + b ----------
// grid: 3 mats * 2 batches * 512 n-chunks(8 tokens) = 3072 blocks, 256 thr
__global__ __launch_bounds__(256) void proj_kernel(
        const float* __restrict__ x, const float* __restrict__ Wt,
        const float* __restrict__ bq, const float* __restrict__ bk,
        const float* __restrict__ bv,
        float* __restrict__ Q, float* __restrict__ K, float* __restrict__ V) {
    const int bx  = blockIdx.x;
    const int mat = bx >> 10;            // /1024
    const int rem = bx & 1023;
    const int b   = rem >> 9;            // /512
    const int n0  = (rem & 511) << 3;    // *8

    const float* W    = Wt + mat * 65536;
    const float* bias = (mat == 0) ? bq : (mat == 1) ? bk : bv;
    float* Out        = (mat == 0) ? Q : (mat == 1) ? K : V;

    __shared__ float xs[256 * 8];
    const int t = threadIdx.x;

    // stage x[b, c=t, n0..n0+7]
    {
        const float* xp = x + ((size_t)(b * 256 + t)) * NN + n0;
        float4 a0 = *(const float4*)xp;
        float4 a1 = *(const float4*)(xp + 4);
        xs[t * 8 + 0] = a0.x; xs[t * 8 + 1] = a0.y; xs[t * 8 + 2] = a0.z; xs[t * 8 + 3] = a0.w;
        xs[t * 8 + 4] = a1.x; xs[t * 8 + 5] = a1.y; xs[t * 8 + 6] = a1.z; xs[t * 8 + 7] = a1.w;
    }
    __syncthreads();

    float acc[8];
    const float bb = bias[t];
#pragma unroll
    for (int j = 0; j < 8; j++) acc[j] = bb;

    for (int c = 0; c < 256; c++) {
        float w = W[c * 256 + t];          // coalesced
        const float* xr = &xs[c * 8];      // uniform -> broadcast
#pragma unroll
        for (int j = 0; j < 8; j++) acc[j] += xr[j] * w;
    }
#pragma unroll
    for (int j = 0; j < 8; j++)
        Out[((size_t)((b << 12) + n0 + j)) * CC + t] = acc[j];
}

// ---------- kernel 3: scores + exact top-k + softmax + AV ----------
// one block = 2 rows (n0, n0+1); grid = B*N/2 = 4096 blocks, 256 thr
__global__ __launch_bounds__(256) void attn_kernel(
        const float* __restrict__ Q, const float* __restrict__ K,
        const float* __restrict__ V, float* __restrict__ out) {
    __shared__ float S[2][NN];          // 32 KB
    __shared__ float qs[2][CC];
    __shared__ unsigned hist[256];
    __shared__ unsigned scan[256];
    __shared__ float fred[256];
    __shared__ int   selIdx[KK];
    __shared__ float selE[KK];
    __shared__ unsigned sh_d, sh_cntgt, sh_umax;
    __shared__ int sh_cnt;

    const int t  = threadIdx.x;
    const int b  = blockIdx.x >> 11;          // 2048 row-pairs per batch
    const int n0 = (blockIdx.x & 2047) << 1;

    qs[0][t] = Q[((size_t)((b << 12) + n0)) * CC + t];
    qs[1][t] = Q[((size_t)((b << 12) + n0 + 1)) * CC + t];
    __syncthreads();

    // ---- score phase: thread t owns m in [16t, 16t+16) ----
    {
        const int m0 = t * 16;
        for (int mj = 0; mj < 16; mj += 4) {
            float acc[4][2];
#pragma unroll
            for (int mi = 0; mi < 4; mi++) { acc[mi][0] = 0.f; acc[mi][1] = 0.f; }
            const float* kp = K + ((size_t)((b << 12) + m0 + mj)) * CC;
            for (int c = 0; c < CC; c += 4) {
                float4 q0 = *(const float4*)&qs[0][c];
                float4 q1 = *(const float4*)&qs[1][c];
#pragma unroll
                for (int mi = 0; mi < 4; mi++) {
                    float4 kv = *(const float4*)(kp + mi * CC + c);
                    acc[mi][0] += kv.x * q0.x + kv.y * q0.y + kv.z * q0.z + kv.w * q0.w;
                    acc[mi][1] += kv.x * q1.x + kv.y * q1.y + kv.z * q1.z + kv.w * q1.w;
                }
            }
#pragma unroll
            for (int mi = 0; mi < 4; mi++) {
                S[0][m0 + mj + mi] = acc[mi][0] * SCALE;
                S[1][m0 + mj + mi] = acc[mi][1] * SCALE;
            }
        }
    }
    __syncthreads();

    // ---- per-row: radix-select top-KK, softmax, AV ----
    for (int r = 0; r < 2; r++) {
        if (t == 0) { sh_cnt = 0; sh_umax = 0u; }
        __syncthreads();

        // row max (for softmax stability)
        {
            unsigned lmax = 0u;
#pragma unroll
            for (int j = 0; j < 16; j++) lmax = max(lmax, fkey(S[r][t * 16 + j]));
            atomicMax(&sh_umax, lmax);
        }

        unsigned prefix = 0u;
        int remaining = KK;
        for (int pass = 0; pass < 4; pass++) {
            const int shift = 24 - 8 * pass;
            hist[t] = 0u;
            __syncthreads();
            for (int j = 0; j < 16; j++) {
                unsigned u = fkey(S[r][t * 16 + j]);
                bool part = (pass == 0) || ((u >> (shift + 8)) == (prefix >> (shift + 8)));
                if (part) atomicAdd(&hist[(u >> shift) & 255u], 1u);
            }
            __syncthreads();
            // suffix sums: scan[d] = count of participants with digit >= d
            scan[t] = hist[t];
            __syncthreads();
            for (int off = 1; off < 256; off <<= 1) {
                unsigned v = (t + off < 256) ? scan[t + off] : 0u;
                __syncthreads();
                scan[t] += v;
                __syncthreads();
            }
            unsigned sufd  = scan[t];
            unsigned sufd1 = (t < 255) ? scan[t + 1] : 0u;
            if (sufd >= (unsigned)remaining && sufd1 < (unsigned)remaining) {
                sh_d = (unsigned)t; sh_cntgt = sufd1;
            }
            __syncthreads();
            prefix |= (sh_d << shift);
            remaining -= (int)sh_cntgt;
            __syncthreads();
        }
        const unsigned T = prefix;    // key of the KK-th largest
        const int need = remaining;   // # of T-valued elems to keep (lowest idx first)

        // stable tie-break: exclusive prefix of per-thread equal counts
        int eqc = 0;
        for (int j = 0; j < 16; j++) if (fkey(S[r][t * 16 + j]) == T) eqc++;
        scan[t] = (unsigned)eqc;
        __syncthreads();
        for (int off = 1; off < 256; off <<= 1) {
            unsigned v = (t >= off) ? scan[t - off] : 0u;
            __syncthreads();
            scan[t] += v;
            __syncthreads();
        }
        const int eqexcl = (int)scan[t] - eqc;

        const float mmax = keyToF(sh_umax);
        float le = 0.f;
        int seen = 0;
        for (int j = 0; j < 16; j++) {
            int m = t * 16 + j;
            float sv = S[r][m];
            unsigned u = fkey(sv);
            bool sel = (u > T) || (u == T && (eqexcl + seen) < need);
            if (u == T) seen++;
            if (sel) {
                float e = expf(sv - mmax);
                int slot = atomicAdd(&sh_cnt, 1);
                selIdx[slot] = m;
                selE[slot] = e;
                le += e;
            }
        }
        fred[t] = le;
        __syncthreads();
        for (int off = 128; off > 0; off >>= 1) {
            if (t < off) fred[t] += fred[t + off];
            __syncthreads();
        }
        const float inv = 1.0f / fred[0];

        // AV gather: coalesced V row reads, channel c = t
        float acc = 0.f;
        const float* vb = V + ((size_t)(b << 12)) * CC + t;
        for (int i = 0; i < KK; i++) {
            int m = selIdx[i];
            float w = selE[i] * inv;
            acc += w * vb[(size_t)m * CC];
        }
        out[(((size_t)(b * CC + t)) << 12) + (n0 + r)] = acc;
        __syncthreads();
    }
}

extern "C" void kernel_launch(void* const* d_in, const int* in_sizes, int n_in,
                              void* d_out, int out_size, void* d_ws, size_t ws_size,
                              hipStream_t stream) {
    const float* x  = (const float*)d_in[0];
    const float* Wq = (const float*)d_in[1];
    const float* bq = (const float*)d_in[2];
    const float* Wk = (const float*)d_in[3];
    const float* bk = (const float*)d_in[4];
    const float* Wv = (const float*)d_in[5];
    const float* bv = (const float*)d_in[6];
    float* out = (float*)d_out;

    float* ws = (float*)d_ws;
    float* Wt = ws;                       // 3*256*256
    float* Q  = Wt + 3 * 65536;           // 2*4096*256
    float* K  = Q + BATCH * NN * CC;
    float* V  = K + BATCH * NN * CC;

    transpose_w<<<768, 256, 0, stream>>>(Wq, Wk, Wv, Wt);
    proj_kernel<<<3 * BATCH * (NN / 8), 256, 0, stream>>>(x, Wt, bq, bk, bv, Q, K, V);
    attn_kernel<<<BATCH * NN / 2, 256, 0, stream>>>(Q, K, V, out);
}

// Round 2
// 423.391 us; speedup vs baseline: 7.5142x; 7.5142x over previous
//
#include <hip/hip_runtime.h>
#include <hip/hip_bf16.h>
#include <math.h>

#define BATCH 2
#define CC    256
#define NN    4096
#define KK    409          // max(1, int(0.1*4096))
#define KCAT  768          // split-fp16: [hi, lo, hi] x [hi, hi, lo]
#define SCALE 0.0625f      // 1/sqrt(256)

typedef _Float16 half8 __attribute__((ext_vector_type(8)));
typedef float    floatx4 __attribute__((ext_vector_type(4)));

// ---------- helpers: order-preserving float<->uint key ----------
__device__ __forceinline__ unsigned fkey(float f) {
    unsigned u = __float_as_uint(f);
    return (u & 0x80000000u) ? ~u : (u | 0x80000000u);
}
__device__ __forceinline__ float keyToF(unsigned k) {
    unsigned u = (k & 0x80000000u) ? (k ^ 0x80000000u) : ~k;
    return __uint_as_float(u);
}

// ---------- kernel 1: transpose the three 256x256 weights ----------
__global__ void transpose_w(const float* __restrict__ Wq,
                            const float* __restrict__ Wk,
                            const float* __restrict__ Wv,
                            float* __restrict__ Wt) {
    int mat = blockIdx.x >> 8;        // 0..2
    int o   = blockIdx.x & 255;
    int c   = threadIdx.x;
    const float* W = (mat == 0) ? Wq : (mat == 1) ? Wk : Wv;
    Wt[mat * 65536 + c * 256 + o] = W[o * 256 + c];
}

// ---------- kernel 2: projections; Q,K -> split-fp16 concat, V -> fp32 ----------
// grid: 3 mats * 2 batches * 512 n-chunks(8 tokens) = 3072 blocks, 256 thr
__global__ __launch_bounds__(256) void proj_kernel(
        const float* __restrict__ x, const float* __restrict__ Wt,
        const float* __restrict__ bq, const float* __restrict__ bk,
        const float* __restrict__ bv,
        _Float16* __restrict__ Qcat, _Float16* __restrict__ Kcat,
        float* __restrict__ V) {
    const int bx  = blockIdx.x;
    const int mat = bx >> 10;            // /1024
    const int rem = bx & 1023;
    const int b   = rem >> 9;            // /512
    const int n0  = (rem & 511) << 3;    // *8

    const float* W    = Wt + mat * 65536;
    const float* bias = (mat == 0) ? bq : (mat == 1) ? bk : bv;

    __shared__ float xs[256 * 8];
    const int t = threadIdx.x;

    {
        const float* xp = x + ((size_t)(b * 256 + t)) * NN + n0;
        float4 a0 = *(const float4*)xp;
        float4 a1 = *(const float4*)(xp + 4);
        xs[t * 8 + 0] = a0.x; xs[t * 8 + 1] = a0.y; xs[t * 8 + 2] = a0.z; xs[t * 8 + 3] = a0.w;
        xs[t * 8 + 4] = a1.x; xs[t * 8 + 5] = a1.y; xs[t * 8 + 6] = a1.z; xs[t * 8 + 7] = a1.w;
    }
    __syncthreads();

    float acc[8];
    const float bb = bias[t];
#pragma unroll
    for (int j = 0; j < 8; j++) acc[j] = bb;

    for (int c = 0; c < 256; c++) {
        float w = W[c * 256 + t];          // coalesced
        const float* xr = &xs[c * 8];      // uniform -> broadcast
#pragma unroll
        for (int j = 0; j < 8; j++) acc[j] += xr[j] * w;
    }

    if (mat == 2) {
#pragma unroll
        for (int j = 0; j < 8; j++)
            V[((size_t)((b << 12) + n0 + j)) * CC + t] = acc[j];
    } else if (mat == 0) {
#pragma unroll
        for (int j = 0; j < 8; j++) {
            _Float16* qc = Qcat + ((size_t)((b << 12) + n0 + j)) * KCAT;
            _Float16 hi = (_Float16)acc[j];
            _Float16 lo = (_Float16)(acc[j] - (float)hi);
            qc[t] = hi; qc[256 + t] = lo; qc[512 + t] = hi;   // [hi, lo, hi]
        }
    } else {
#pragma unroll
        for (int j = 0; j < 8; j++) {
            _Float16* kc = Kcat + ((size_t)((b << 12) + n0 + j)) * KCAT;
            _Float16 hi = (_Float16)acc[j];
            _Float16 lo = (_Float16)(acc[j] - (float)hi);
            kc[t] = hi; kc[256 + t] = hi; kc[512 + t] = lo;   // [hi, hi, lo]
        }
    }
}

// ---------- kernel 3: S = (Qcat @ Kcat^T) * SCALE via MFMA f16 ----------
// grid (64, 64, 2); block 256 = 4 waves (2x2), block tile 64x64, wave 32x32
__global__ __launch_bounds__(256) void score_gemm(
        const _Float16* __restrict__ Qcat, const _Float16* __restrict__ Kcat,
        float* __restrict__ S) {
    __shared__ _Float16 As[64][72];   // +8 pad: breaks 128B-stride bank aliasing
    __shared__ _Float16 Bs[64][72];

    const int t    = threadIdx.x;
    const int wave = t >> 6;
    const int l    = t & 63;
    const int wr   = wave >> 1;          // 0..1
    const int wc   = wave & 1;           // 0..1
    const int bxn  = blockIdx.x;         // col tile (K side)
    const int bym  = blockIdx.y;         // row tile (Q side)
    const int b    = blockIdx.z;

    const int r = t >> 2;                // staging row 0..63
    const int q = t & 3;                 // staging quarter

    const _Float16* Abase = Qcat + ((size_t)((b << 12) + bym * 64 + r)) * KCAT;
    const _Float16* Bbase = Kcat + ((size_t)((b << 12) + bxn * 64 + r)) * KCAT;

    floatx4 acc[2][2];
#pragma unroll
    for (int i = 0; i < 2; i++)
#pragma unroll
        for (int j = 0; j < 2; j++) acc[i][j] = (floatx4)0.0f;

    const int rowA = (l & 15);
    const int koff = (l >> 4) * 8;

    for (int kc = 0; kc < KCAT; kc += 64) {
        // stage 64x64 of A and B
        {
            const uint4* ap = (const uint4*)(Abase + kc + q * 16);
            const uint4* bp = (const uint4*)(Bbase + kc + q * 16);
            uint4 a0 = ap[0], a1 = ap[1];
            uint4 b0 = bp[0], b1 = bp[1];
            *(uint4*)&As[r][q * 16]     = a0;
            *(uint4*)&As[r][q * 16 + 8] = a1;
            *(uint4*)&Bs[r][q * 16]     = b0;
            *(uint4*)&Bs[r][q * 16 + 8] = b1;
        }
        __syncthreads();
#pragma unroll
        for (int ks = 0; ks < 64; ks += 32) {
            half8 af[2], bf[2];
#pragma unroll
            for (int mi = 0; mi < 2; mi++)
                af[mi] = *(const half8*)&As[wr * 32 + mi * 16 + rowA][ks + koff];
#pragma unroll
            for (int ni = 0; ni < 2; ni++)
                bf[ni] = *(const half8*)&Bs[wc * 32 + ni * 16 + rowA][ks + koff];
#pragma unroll
            for (int mi = 0; mi < 2; mi++)
#pragma unroll
                for (int ni = 0; ni < 2; ni++)
                    acc[mi][ni] = __builtin_amdgcn_mfma_f32_16x16x32_f16(
                        af[mi], bf[ni], acc[mi][ni], 0, 0, 0);
        }
        __syncthreads();
    }

    // epilogue: C/D layout col=lane&15, row=(lane>>4)*4+reg
    float* Sb = S + ((size_t)b << 24);
#pragma unroll
    for (int mi = 0; mi < 2; mi++)
#pragma unroll
        for (int ni = 0; ni < 2; ni++) {
            int col = bxn * 64 + wc * 32 + ni * 16 + (l & 15);
#pragma unroll
            for (int rg = 0; rg < 4; rg++) {
                int row = bym * 64 + wr * 32 + mi * 16 + (l >> 4) * 4 + rg;
                Sb[((size_t)row << 12) + col] = acc[mi][ni][rg] * SCALE;
            }
        }
}

// ---------- kernel 4: per-row exact top-k + softmax + AV ----------
// one block per row; grid = B*N = 8192 blocks, 256 thr
__global__ __launch_bounds__(256) void select_av(
        const float* __restrict__ S, const float* __restrict__ V,
        float* __restrict__ out) {
    __shared__ unsigned hist[256];
    __shared__ unsigned scan[256];
    __shared__ float fred[256];
    __shared__ int   selIdx[KK];
    __shared__ float selE[KK];
    __shared__ unsigned sh_d, sh_cntgt, sh_umax;
    __shared__ int sh_cnt;

    const int t   = threadIdx.x;
    const int b   = blockIdx.x >> 12;
    const int row = blockIdx.x & 4095;

    const float* Srow = S + ((size_t)blockIdx.x << 12);

    // thread t owns contiguous indices [16t, 16t+16) -> proven tie-break logic
    float val[16];
    {
        const float4* sp = (const float4*)(Srow + t * 16);
#pragma unroll
        for (int jj = 0; jj < 4; jj++) {
            float4 v = sp[jj];
            val[jj * 4 + 0] = v.x; val[jj * 4 + 1] = v.y;
            val[jj * 4 + 2] = v.z; val[jj * 4 + 3] = v.w;
        }
    }

    if (t == 0) { sh_cnt = 0; sh_umax = 0u; }
    __syncthreads();

    {
        unsigned lmax = 0u;
#pragma unroll
        for (int j = 0; j < 16; j++) lmax = max(lmax, fkey(val[j]));
        atomicMax(&sh_umax, lmax);
    }

    unsigned prefix = 0u;
    int remaining = KK;
    for (int pass = 0; pass < 4; pass++) {
        const int shift = 24 - 8 * pass;
        hist[t] = 0u;
        __syncthreads();
#pragma unroll
        for (int j = 0; j < 16; j++) {
            unsigned u = fkey(val[j]);
            bool part = (pass == 0) || ((u >> (shift + 8)) == (prefix >> (shift + 8)));
            if (part) atomicAdd(&hist[(u >> shift) & 255u], 1u);
        }
        __syncthreads();
        scan[t] = hist[t];
        __syncthreads();
        for (int off = 1; off < 256; off <<= 1) {
            unsigned v = (t + off < 256) ? scan[t + off] : 0u;
            __syncthreads();
            scan[t] += v;
            __syncthreads();
        }
        unsigned sufd  = scan[t];
        unsigned sufd1 = (t < 255) ? scan[t + 1] : 0u;
        if (sufd >= (unsigned)remaining && sufd1 < (unsigned)remaining) {
            sh_d = (unsigned)t; sh_cntgt = sufd1;
        }
        __syncthreads();
        prefix |= (sh_d << shift);
        remaining -= (int)sh_cntgt;
        __syncthreads();
    }
    const unsigned T = prefix;
    const int need = remaining;

    int eqc = 0;
#pragma unroll
    for (int j = 0; j < 16; j++) if (fkey(val[j]) == T) eqc++;
    scan[t] = (unsigned)eqc;
    __syncthreads();
    for (int off = 1; off < 256; off <<= 1) {
        unsigned v = (t >= off) ? scan[t - off] : 0u;
        __syncthreads();
        scan[t] += v;
        __syncthreads();
    }
    const int eqexcl = (int)scan[t] - eqc;

    const float mmax = keyToF(sh_umax);
    float le = 0.f;
    int seen = 0;
#pragma unroll
    for (int j = 0; j < 16; j++) {
        int m = t * 16 + j;
        float sv = val[j];
        unsigned u = fkey(sv);
        bool sel = (u > T) || (u == T && (eqexcl + seen) < need);
        if (u == T) seen++;
        if (sel) {
            float e = expf(sv - mmax);
            int slot = atomicAdd(&sh_cnt, 1);
            selIdx[slot] = m;
            selE[slot] = e;
            le += e;
        }
    }
    fred[t] = le;
    __syncthreads();
    for (int off = 128; off > 0; off >>= 1) {
        if (t < off) fred[t] += fred[t + off];
        __syncthreads();
    }
    const float inv = 1.0f / fred[0];

    // AV gather: channel c = t, coalesced V row reads from L2
    float acc = 0.f;
    const float* vb = V + (((size_t)b << 12)) * CC + t;
    int i = 0;
    for (; i + 4 <= KK; i += 4) {
        int   m0 = selIdx[i],     m1 = selIdx[i + 1];
        int   m2 = selIdx[i + 2], m3 = selIdx[i + 3];
        float w0 = selE[i],     w1 = selE[i + 1];
        float w2 = selE[i + 2], w3 = selE[i + 3];
        float v0 = vb[(size_t)m0 * CC];
        float v1 = vb[(size_t)m1 * CC];
        float v2 = vb[(size_t)m2 * CC];
        float v3 = vb[(size_t)m3 * CC];
        acc += w0 * v0 + w1 * v1 + w2 * v2 + w3 * v3;
    }
    for (; i < KK; i++) acc += selE[i] * vb[(size_t)selIdx[i] * CC];
    acc *= inv;

    out[(((size_t)(b * CC + t)) << 12) + row] = acc;
}

extern "C" void kernel_launch(void* const* d_in, const int* in_sizes, int n_in,
                              void* d_out, int out_size, void* d_ws, size_t ws_size,
                              hipStream_t stream) {
    const float* x  = (const float*)d_in[0];
    const float* Wq = (const float*)d_in[1];
    const float* bq = (const float*)d_in[2];
    const float* Wk = (const float*)d_in[3];
    const float* bk = (const float*)d_in[4];
    const float* Wv = (const float*)d_in[5];
    const float* bv = (const float*)d_in[6];
    float* out = (float*)d_out;

    char* ws = (char*)d_ws;
    float*    Wt   = (float*)ws;                               // 768 KB
    float*    V    = (float*)(ws + 786432);                    // 8 MB
    _Float16* Qcat = (_Float16*)(ws + 786432 + 8388608);       // 12.6 MB
    _Float16* Kcat = (_Float16*)(ws + 786432 + 8388608 + 12582912);
    float*    S    = (float*)(ws + 786432 + 8388608 + 2 * 12582912);  // 128 MB

    transpose_w<<<768, 256, 0, stream>>>(Wq, Wk, Wv, Wt);
    proj_kernel<<<3 * BATCH * (NN / 8), 256, 0, stream>>>(x, Wt, bq, bk, bv,
                                                          Qcat, Kcat, V);
    score_gemm<<<dim3(64, 64, BATCH), 256, 0, stream>>>(Qcat, Kcat, S);
    select_av<<<BATCH * NN, 256, 0, stream>>>(S, V, out);
}

// Round 3
// 353.530 us; speedup vs baseline: 8.9991x; 1.1976x over previous
//
#include <hip/hip_runtime.h>
#include <hip/hip_bf16.h>
#include <math.h>

#define BATCH 2
#define CC    256
#define NN    4096
#define KK    409          // max(1, int(0.1*4096))
#define KCAT  768          // split-fp16: [hi, lo, hi] x [hi, hi, lo]
#define SCALE 0.0625f      // 1/sqrt(256)
#define PSTRIDE 8192       // P row stride in halfs (P aliases S rows' first half)

typedef _Float16 half8 __attribute__((ext_vector_type(8)));
typedef float    floatx4 __attribute__((ext_vector_type(4)));

// ---------- helpers: order-preserving float<->uint key ----------
__device__ __forceinline__ unsigned fkey(float f) {
    unsigned u = __float_as_uint(f);
    return (u & 0x80000000u) ? ~u : (u | 0x80000000u);
}
__device__ __forceinline__ float keyToF(unsigned k) {
    unsigned u = (k & 0x80000000u) ? (k ^ 0x80000000u) : ~k;
    return __uint_as_float(u);
}

// ---------- kernel 1: transpose the three 256x256 weights ----------
__global__ void transpose_w(const float* __restrict__ Wq,
                            const float* __restrict__ Wk,
                            const float* __restrict__ Wv,
                            float* __restrict__ Wt) {
    int mat = blockIdx.x >> 8;
    int o   = blockIdx.x & 255;
    int c   = threadIdx.x;
    const float* W = (mat == 0) ? Wq : (mat == 1) ? Wk : Wv;
    Wt[mat * 65536 + c * 256 + o] = W[o * 256 + c];
}

// ---------- kernel 2: projections; Q,K -> split-fp16 concat, V -> fp16 transposed ----------
__global__ __launch_bounds__(256) void proj_kernel(
        const float* __restrict__ x, const float* __restrict__ Wt,
        const float* __restrict__ bq, const float* __restrict__ bk,
        const float* __restrict__ bv,
        _Float16* __restrict__ Qcat, _Float16* __restrict__ Kcat,
        _Float16* __restrict__ Vt) {
    const int bx  = blockIdx.x;
    const int mat = bx >> 10;
    const int rem = bx & 1023;
    const int b   = rem >> 9;
    const int n0  = (rem & 511) << 3;

    const float* W    = Wt + mat * 65536;
    const float* bias = (mat == 0) ? bq : (mat == 1) ? bk : bv;

    __shared__ float xs[256 * 8];
    const int t = threadIdx.x;

    {
        const float* xp = x + ((size_t)(b * 256 + t)) * NN + n0;
        float4 a0 = *(const float4*)xp;
        float4 a1 = *(const float4*)(xp + 4);
        xs[t * 8 + 0] = a0.x; xs[t * 8 + 1] = a0.y; xs[t * 8 + 2] = a0.z; xs[t * 8 + 3] = a0.w;
        xs[t * 8 + 4] = a1.x; xs[t * 8 + 5] = a1.y; xs[t * 8 + 6] = a1.z; xs[t * 8 + 7] = a1.w;
    }
    __syncthreads();

    float acc[8];
    const float bb = bias[t];
#pragma unroll
    for (int j = 0; j < 8; j++) acc[j] = bb;

    for (int c = 0; c < 256; c++) {
        float w = W[c * 256 + t];
        const float* xr = &xs[c * 8];
#pragma unroll
        for (int j = 0; j < 8; j++) acc[j] += xr[j] * w;
    }

    if (mat == 2) {
        // Vt[b][c=t][m=n0+j], fp16, one contiguous 16B store per thread
        half8 v;
#pragma unroll
        for (int j = 0; j < 8; j++) v[j] = (_Float16)acc[j];
        *(half8*)(Vt + ((size_t)((b << 8) + t)) * NN + n0) = v;
    } else if (mat == 0) {
#pragma unroll
        for (int j = 0; j < 8; j++) {
            _Float16* qc = Qcat + ((size_t)((b << 12) + n0 + j)) * KCAT;
            _Float16 hi = (_Float16)acc[j];
            _Float16 lo = (_Float16)(acc[j] - (float)hi);
            qc[t] = hi; qc[256 + t] = lo; qc[512 + t] = hi;   // [hi, lo, hi]
        }
    } else {
#pragma unroll
        for (int j = 0; j < 8; j++) {
            _Float16* kc = Kcat + ((size_t)((b << 12) + n0 + j)) * KCAT;
            _Float16 hi = (_Float16)acc[j];
            _Float16 lo = (_Float16)(acc[j] - (float)hi);
            kc[t] = hi; kc[256 + t] = hi; kc[512 + t] = lo;   // [hi, hi, lo]
        }
    }
}

// ---------- kernel 3: S = (Qcat @ Kcat^T) * SCALE via MFMA f16, 128x128 tile ----------
// grid (32, 32, 2); 4 waves (2x2), wave tile 64x64 (4x4 frags of 16x16x32)
__global__ __launch_bounds__(256) void score_gemm(
        const _Float16* __restrict__ Qcat, const _Float16* __restrict__ Kcat,
        float* __restrict__ S) {
    __shared__ _Float16 As[128][72];
    __shared__ _Float16 Bs[128][72];

    const int t    = threadIdx.x;
    const int wave = t >> 6;
    const int l    = t & 63;
    const int wr   = wave >> 1;
    const int wc   = wave & 1;
    const int bxn  = blockIdx.x;
    const int bym  = blockIdx.y;
    const int b    = blockIdx.z;

    const int r = t >> 1;               // 0..127
    const int h = t & 1;                // 0..1

    const _Float16* Abase = Qcat + ((size_t)((b << 12) + bym * 128 + r)) * KCAT + h * 32;
    const _Float16* Bbase = Kcat + ((size_t)((b << 12) + bxn * 128 + r)) * KCAT + h * 32;

    floatx4 acc[4][4];
#pragma unroll
    for (int i = 0; i < 4; i++)
#pragma unroll
        for (int j = 0; j < 4; j++) acc[i][j] = (floatx4)0.0f;

    const int rowA = l & 15;
    const int koff = (l >> 4) * 8;

    for (int kc = 0; kc < KCAT; kc += 64) {
        const uint4* ap = (const uint4*)(Abase + kc);
        const uint4* bp = (const uint4*)(Bbase + kc);
        uint4 a0 = ap[0], a1 = ap[1], a2 = ap[2], a3 = ap[3];
        uint4 b0 = bp[0], b1 = bp[1], b2 = bp[2], b3 = bp[3];
        *(uint4*)&As[r][h * 32]      = a0;
        *(uint4*)&As[r][h * 32 + 8]  = a1;
        *(uint4*)&As[r][h * 32 + 16] = a2;
        *(uint4*)&As[r][h * 32 + 24] = a3;
        *(uint4*)&Bs[r][h * 32]      = b0;
        *(uint4*)&Bs[r][h * 32 + 8]  = b1;
        *(uint4*)&Bs[r][h * 32 + 16] = b2;
        *(uint4*)&Bs[r][h * 32 + 24] = b3;
        __syncthreads();
#pragma unroll
        for (int ks = 0; ks < 64; ks += 32) {
            half8 af[4], bf[4];
#pragma unroll
            for (int mi = 0; mi < 4; mi++)
                af[mi] = *(const half8*)&As[wr * 64 + mi * 16 + rowA][ks + koff];
#pragma unroll
            for (int ni = 0; ni < 4; ni++)
                bf[ni] = *(const half8*)&Bs[wc * 64 + ni * 16 + rowA][ks + koff];
#pragma unroll
            for (int mi = 0; mi < 4; mi++)
#pragma unroll
                for (int ni = 0; ni < 4; ni++)
                    acc[mi][ni] = __builtin_amdgcn_mfma_f32_16x16x32_f16(
                        af[mi], bf[ni], acc[mi][ni], 0, 0, 0);
        }
        __syncthreads();
    }

    float* Sb = S + ((size_t)b << 24);
#pragma unroll
    for (int mi = 0; mi < 4; mi++)
#pragma unroll
        for (int ni = 0; ni < 4; ni++) {
            int col = bxn * 128 + wc * 64 + ni * 16 + (l & 15);
#pragma unroll
            for (int rg = 0; rg < 4; rg++) {
                int row = bym * 128 + wr * 64 + mi * 16 + (l >> 4) * 4 + rg;
                Sb[((size_t)row << 12) + col] = acc[mi][ni][rg] * SCALE;
            }
        }
}

// ---------- kernel 4: per-row exact top-k + softmax -> dense fp16 P row ----------
// one block per row; grid = B*N = 8192 blocks, 256 thr
// P aliases S: P row n occupies the first 8192 halfs of S row n (read-before-write safe)
__global__ __launch_bounds__(256) void select_scatter(
        const float* __restrict__ S, _Float16* __restrict__ P) {
    __shared__ unsigned hist[256];
    __shared__ unsigned scan[256];
    __shared__ unsigned candKey[NN];     // worst case: all elems in one bin
    __shared__ unsigned wred[4];
    __shared__ float    wsum[4];
    __shared__ unsigned sh_d, sh_cntgt;
    __shared__ int      sh_ncand;

    const int t = threadIdx.x;
    const int l = t & 63;
    const int w = t >> 6;

    // load + key (thread t owns indices 16t..16t+15)
    unsigned ukey[16];
    {
        const float*  Srow = S + ((size_t)blockIdx.x << 12);
        const float4* sp   = (const float4*)(Srow + t * 16);
#pragma unroll
        for (int jj = 0; jj < 4; jj++) {
            float4 v = sp[jj];
            ukey[jj * 4 + 0] = fkey(v.x); ukey[jj * 4 + 1] = fkey(v.y);
            ukey[jj * 4 + 2] = fkey(v.z); ukey[jj * 4 + 3] = fkey(v.w);
        }
    }

    // row max via wave reduce
    unsigned lmax = 0u;
#pragma unroll
    for (int j = 0; j < 16; j++) lmax = max(lmax, ukey[j]);
#pragma unroll
    for (int off = 32; off > 0; off >>= 1) {
        unsigned o = __shfl_down(lmax, off);
        if (l + off < 64) lmax = max(lmax, o);
    }
    if (l == 0) wred[w] = lmax;

    hist[t] = 0u;
    if (t == 0) sh_ncand = 0;
    __syncthreads();
    const unsigned umax = max(max(wred[0], wred[1]), max(wred[2], wred[3]));

    // ---- pass 1: 256-bin histogram over top byte ----
#pragma unroll
    for (int j = 0; j < 16; j++) atomicAdd(&hist[ukey[j] >> 24], 1u);
    __syncthreads();

    int rem = KK;
    unsigned prefix = 0u;

    // suffix-scan + threshold-digit find (wave shuffles, 3 barriers)
    auto find_digit = [&](int remv) {
        unsigned v = hist[t];
#pragma unroll
        for (int off = 1; off < 64; off <<= 1) {
            unsigned o = __shfl_down(v, off);
            if (l + off < 64) v += o;
        }
        if (l == 0) wred[w] = v;
        __syncthreads();
        unsigned add = 0u;
#pragma unroll
        for (int w2 = 0; w2 < 4; w2++) if (w2 > w) add += wred[w2];
        scan[t] = v + add;
        __syncthreads();
        unsigned sufd  = scan[t];
        unsigned sufd1 = (t < 255) ? scan[t + 1] : 0u;
        if (sufd >= (unsigned)remv && sufd1 < (unsigned)remv) {
            sh_d = (unsigned)t; sh_cntgt = sufd1;
        }
        __syncthreads();
    };

    find_digit(rem);
    const unsigned d1 = sh_d;
    rem -= (int)sh_cntgt;
    prefix = d1 << 24;

    // compact candidates (top byte == d1)
#pragma unroll
    for (int j = 0; j < 16; j++) {
        if ((ukey[j] >> 24) == d1) {
            int slot = atomicAdd(&sh_ncand, 1);
            candKey[slot] = ukey[j];
        }
    }
    __syncthreads();
    const int nc = sh_ncand;

    // ---- passes 2..4 over candidates only ----
    for (int pass = 1; pass < 4; pass++) {
        const int shift = 24 - 8 * pass;
        hist[t] = 0u;
        __syncthreads();
        for (int i = t; i < nc; i += 256) {
            unsigned u = candKey[i];
            if ((u >> (shift + 8)) == (prefix >> (shift + 8)))
                atomicAdd(&hist[(u >> shift) & 255u], 1u);
        }
        __syncthreads();
        find_digit(rem);
        prefix |= (sh_d << shift);
        rem -= (int)sh_cntgt;
    }
    const unsigned T = prefix;
    const int need = rem;

    // stable tie-break: exclusive prefix of per-thread equal counts (wave scan)
    int eqc = 0;
#pragma unroll
    for (int j = 0; j < 16; j++) if (ukey[j] == T) eqc++;
    int vinc = eqc;
#pragma unroll
    for (int off = 1; off < 64; off <<= 1) {
        int o = __shfl_up(vinc, off);
        if (l >= off) vinc += o;
    }
    if (l == 63) wred[w] = (unsigned)vinc;
    __syncthreads();
    int addlow = 0;
#pragma unroll
    for (int w2 = 0; w2 < 4; w2++) if (w2 < w) addlow += (int)wred[w2];
    const int eqexcl = vinc - eqc + addlow;

    // selection + exp (all thread-local: thread owns slots 16t..16t+15)
    const float mmax = keyToF(umax);
    float pv[16];
    float le = 0.f;
    int seen = 0;
#pragma unroll
    for (int j = 0; j < 16; j++) {
        unsigned u = ukey[j];
        bool sel = (u > T) || (u == T && (eqexcl + seen) < need);
        if (u == T) seen++;
        float e = 0.f;
        if (sel) { e = expf(keyToF(u) - mmax); le += e; }
        pv[j] = e;
    }

    // sum reduce
#pragma unroll
    for (int off = 32; off > 0; off >>= 1) {
        float o = __shfl_down(le, off);
        if (l + off < 64) le += o;
    }
    if (l == 0) wsum[w] = le;
    __syncthreads();
    const float inv = 1.0f / (wsum[0] + wsum[1] + wsum[2] + wsum[3]);

    // write dense fp16 P row (coalesced 2x16B per thread)
    half8 ra, rb;
#pragma unroll
    for (int j = 0; j < 8; j++) {
        ra[j] = (_Float16)(pv[j] * inv);
        rb[j] = (_Float16)(pv[j + 8] * inv);
    }
    _Float16* Pr = P + (size_t)blockIdx.x * PSTRIDE + t * 16;
    *(half8*)Pr       = ra;
    *(half8*)(Pr + 8) = rb;
}

// ---------- kernel 5: out[b][c][n] = sum_m Vt[c][m] * P[n][m] via MFMA f16 ----------
// grid (64 n-tiles, 4 c-tiles, 2); 4 waves (2x2), wave tile 32x32
__global__ __launch_bounds__(256) void av_gemm(
        const _Float16* __restrict__ Vt, const _Float16* __restrict__ P,
        float* __restrict__ out) {
    __shared__ _Float16 As[64][72];
    __shared__ _Float16 Bs[64][72];

    const int t    = threadIdx.x;
    const int wave = t >> 6;
    const int l    = t & 63;
    const int wr   = wave >> 1;
    const int wc   = wave & 1;
    const int bxn  = blockIdx.x;
    const int byc  = blockIdx.y;
    const int b    = blockIdx.z;

    const int r = t >> 2;
    const int q = t & 3;

    const _Float16* Abase = Vt + ((size_t)((b << 8) + byc * 64 + r)) * NN + q * 16;
    const _Float16* Bbase = P + ((size_t)(b * NN + bxn * 64 + r)) * PSTRIDE + q * 16;

    floatx4 acc[2][2];
#pragma unroll
    for (int i = 0; i < 2; i++)
#pragma unroll
        for (int j = 0; j < 2; j++) acc[i][j] = (floatx4)0.0f;

    const int rowA = l & 15;
    const int koff = (l >> 4) * 8;

    for (int kc = 0; kc < NN; kc += 64) {
        const uint4* ap = (const uint4*)(Abase + kc);
        const uint4* bp = (const uint4*)(Bbase + kc);
        uint4 a0 = ap[0], a1 = ap[1];
        uint4 b0 = bp[0], b1 = bp[1];
        *(uint4*)&As[r][q * 16]     = a0;
        *(uint4*)&As[r][q * 16 + 8] = a1;
        *(uint4*)&Bs[r][q * 16]     = b0;
        *(uint4*)&Bs[r][q * 16 + 8] = b1;
        __syncthreads();
#pragma unroll
        for (int ks = 0; ks < 64; ks += 32) {
            half8 af[2], bf[2];
#pragma unroll
            for (int mi = 0; mi < 2; mi++)
                af[mi] = *(const half8*)&As[wr * 32 + mi * 16 + rowA][ks + koff];
#pragma unroll
            for (int ni = 0; ni < 2; ni++)
                bf[ni] = *(const half8*)&Bs[wc * 32 + ni * 16 + rowA][ks + koff];
#pragma unroll
            for (int mi = 0; mi < 2; mi++)
#pragma unroll
                for (int ni = 0; ni < 2; ni++)
                    acc[mi][ni] = __builtin_amdgcn_mfma_f32_16x16x32_f16(
                        af[mi], bf[ni], acc[mi][ni], 0, 0, 0);
        }
        __syncthreads();
    }

    // epilogue: row = c, col = n -> coalesced out[b][c][n]
#pragma unroll
    for (int mi = 0; mi < 2; mi++)
#pragma unroll
        for (int ni = 0; ni < 2; ni++) {
            int col = bxn * 64 + wc * 32 + ni * 16 + (l & 15);
#pragma unroll
            for (int rg = 0; rg < 4; rg++) {
                int row = byc * 64 + wr * 32 + mi * 16 + (l >> 4) * 4 + rg;
                out[((size_t)((b << 8) + row) << 12) + col] = acc[mi][ni][rg];
            }
        }
}

extern "C" void kernel_launch(void* const* d_in, const int* in_sizes, int n_in,
                              void* d_out, int out_size, void* d_ws, size_t ws_size,
                              hipStream_t stream) {
    const float* x  = (const float*)d_in[0];
    const float* Wq = (const float*)d_in[1];
    const float* bq = (const float*)d_in[2];
    const float* Wk = (const float*)d_in[3];
    const float* bk = (const float*)d_in[4];
    const float* Wv = (const float*)d_in[5];
    const float* bv = (const float*)d_in[6];
    float* out = (float*)d_out;

    char* ws = (char*)d_ws;
    float*    Wt   = (float*)ws;                                   // 0.75 MB
    float*    S    = (float*)(ws + 786432);                        // 128 MB
    _Float16* Qcat = (_Float16*)(ws + 786432 + 134217728);         // 12 MB
    _Float16* Kcat = (_Float16*)(ws + 786432 + 134217728 + 12582912);
    _Float16* Vt   = (_Float16*)(ws + 786432 + 134217728 + 2 * 12582912); // 4 MB
    _Float16* P    = (_Float16*)S;   // aliases S rows (first 8192 halfs each)

    transpose_w<<<768, 256, 0, stream>>>(Wq, Wk, Wv, Wt);
    proj_kernel<<<3 * BATCH * (NN / 8), 256, 0, stream>>>(x, Wt, bq, bk, bv,
                                                          Qcat, Kcat, Vt);
    score_gemm<<<dim3(32, 32, BATCH), 256, 0, stream>>>(Qcat, Kcat, S);
    select_scatter<<<BATCH * NN, 256, 0, stream>>>(S, P);
    av_gemm<<<dim3(64, 4, BATCH), 256, 0, stream>>>(Vt, P, out);
}

// Round 4
// 288.795 us; speedup vs baseline: 11.0163x; 1.2242x over previous
//
#include <hip/hip_runtime.h>
#include <hip/hip_bf16.h>
#include <math.h>

#define BATCH 2
#define CC    256
#define NN    4096
#define KK    409          // max(1, int(0.1*4096))
#define KCAT  768          // split-fp16 concat K
#define SCALE 0.0625f      // 1/sqrt(256)
#define PSTRIDE 8192       // P row stride in halfs (P aliases S rows)

typedef _Float16 half8 __attribute__((ext_vector_type(8)));
typedef float    floatx4 __attribute__((ext_vector_type(4)));

// ---------- helpers: order-preserving float<->uint key ----------
__device__ __forceinline__ unsigned fkey(float f) {
    unsigned u = __float_as_uint(f);
    return (u & 0x80000000u) ? ~u : (u | 0x80000000u);
}
__device__ __forceinline__ float keyToF(unsigned k) {
    unsigned u = (k & 0x80000000u) ? (k ^ 0x80000000u) : ~k;
    return __uint_as_float(u);
}

// ---------- kernel 1: x[b][c][n] f32 -> xcat[b*N+n][768] = [hi, lo, hi] ----------
// grid (64 n-tiles, 4 c-tiles, 2 b); 256 thr; 64x64 LDS transpose tile
__global__ __launch_bounds__(256) void xpose_kernel(
        const float* __restrict__ x, _Float16* __restrict__ xcat) {
    __shared__ float xs[64][68];     // 68: 16B-aligned rows, conflict-light
    const int t  = threadIdx.x;
    const int n0 = blockIdx.x * 64;
    const int c0 = blockIdx.y * 64;
    const int b  = blockIdx.z;

    {
        const int ci = t >> 2;
        const int j  = (t & 3) * 16;
        const float* xp = x + ((size_t)((b << 8) + c0 + ci)) * NN + n0 + j;
        float4 a0 = ((const float4*)xp)[0];
        float4 a1 = ((const float4*)xp)[1];
        float4 a2 = ((const float4*)xp)[2];
        float4 a3 = ((const float4*)xp)[3];
        *(float4*)&xs[ci][j]      = a0;
        *(float4*)&xs[ci][j + 4]  = a1;
        *(float4*)&xs[ci][j + 8]  = a2;
        *(float4*)&xs[ci][j + 12] = a3;
    }
    __syncthreads();

    const int n = t >> 2;            // 0..63
    const int g0 = t & 3;
    _Float16* xr = xcat + ((size_t)(b * NN + n0 + n)) * KCAT + c0;
#pragma unroll
    for (int gg = 0; gg < 2; gg++) {
        int g = g0 + gg * 4;         // 0..7, 8 channels each
        half8 hi, lo;
#pragma unroll
        for (int k = 0; k < 8; k++) {
            float v = xs[g * 8 + k][n];
            _Float16 h = (_Float16)v;
            hi[k] = h;
            lo[k] = (_Float16)(v - (float)h);
        }
        *(half8*)(xr + g * 8)       = hi;
        *(half8*)(xr + 256 + g * 8) = lo;
        *(half8*)(xr + 512 + g * 8) = hi;
    }
}

// ---------- kernel 2: W[o][c] -> Wcat[mat][o][768] = [whi, whi, wlo] ----------
__global__ void wcat_kernel(const float* __restrict__ Wq,
                            const float* __restrict__ Wk,
                            const float* __restrict__ Wv,
                            _Float16* __restrict__ Wcat) {
    int mat = blockIdx.x >> 8;
    int o   = blockIdx.x & 255;
    int c   = threadIdx.x;
    const float* W = (mat == 0) ? Wq : (mat == 1) ? Wk : Wv;
    float v = W[o * 256 + c];
    _Float16 hi = (_Float16)v;
    _Float16 lo = (_Float16)(v - (float)hi);
    _Float16* wr = Wcat + ((size_t)(mat * 256 + o)) * KCAT;
    wr[c] = hi; wr[256 + c] = hi; wr[512 + c] = lo;
}

// ---------- kernel 3: projections via MFMA, 128x128 tile, K=768 ----------
// grid (128 tiles, 1, 3 mats); mats 0/1: out rows=tokens(8192) cols=chan(256)
// mat 2: A=Wvcat rows=chan(256), B=xcat cols=tokens(8192) -> Vt layout direct
__global__ __launch_bounds__(256) void proj_gemm(
        const _Float16* __restrict__ xcat, const _Float16* __restrict__ Wcat,
        const float* __restrict__ bq, const float* __restrict__ bk,
        const float* __restrict__ bv,
        _Float16* __restrict__ Qcat, _Float16* __restrict__ Kcat,
        _Float16* __restrict__ Vt) {
    __shared__ _Float16 As[128][72];
    __shared__ _Float16 Bs[128][72];

    const int t    = threadIdx.x;
    const int wave = t >> 6;
    const int l    = t & 63;
    const int wr   = wave >> 1;
    const int wc   = wave & 1;
    const int mat  = blockIdx.z;

    int bym, bxn;
    if (mat < 2) { bym = blockIdx.x >> 1; bxn = blockIdx.x & 1; }
    else         { bym = blockIdx.x & 1;  bxn = blockIdx.x >> 1; }

    const int r = t >> 1;
    const int h = t & 1;

    const _Float16* Abase;
    const _Float16* Bbase;
    if (mat < 2) {
        Abase = xcat + ((size_t)(bym * 128 + r)) * KCAT + h * 32;
        Bbase = Wcat + ((size_t)(mat * 256 + bxn * 128 + r)) * KCAT + h * 32;
    } else {
        Abase = Wcat + ((size_t)(512 + bym * 128 + r)) * KCAT + h * 32;
        Bbase = xcat + ((size_t)(bxn * 128 + r)) * KCAT + h * 32;
    }

    floatx4 acc[4][4];
#pragma unroll
    for (int i = 0; i < 4; i++)
#pragma unroll
        for (int j = 0; j < 4; j++) acc[i][j] = (floatx4)0.0f;

    const int rowA = l & 15;
    const int koff = (l >> 4) * 8;

    for (int kc = 0; kc < KCAT; kc += 64) {
        const uint4* ap = (const uint4*)(Abase + kc);
        const uint4* bp = (const uint4*)(Bbase + kc);
        uint4 a0 = ap[0], a1 = ap[1], a2 = ap[2], a3 = ap[3];
        uint4 b0 = bp[0], b1 = bp[1], b2 = bp[2], b3 = bp[3];
        *(uint4*)&As[r][h * 32]      = a0;
        *(uint4*)&As[r][h * 32 + 8]  = a1;
        *(uint4*)&As[r][h * 32 + 16] = a2;
        *(uint4*)&As[r][h * 32 + 24] = a3;
        *(uint4*)&Bs[r][h * 32]      = b0;
        *(uint4*)&Bs[r][h * 32 + 8]  = b1;
        *(uint4*)&Bs[r][h * 32 + 16] = b2;
        *(uint4*)&Bs[r][h * 32 + 24] = b3;
        __syncthreads();
#pragma unroll
        for (int ks = 0; ks < 64; ks += 32) {
            half8 af[4], bf[4];
#pragma unroll
            for (int mi = 0; mi < 4; mi++)
                af[mi] = *(const half8*)&As[wr * 64 + mi * 16 + rowA][ks + koff];
#pragma unroll
            for (int ni = 0; ni < 4; ni++)
                bf[ni] = *(const half8*)&Bs[wc * 64 + ni * 16 + rowA][ks + koff];
#pragma unroll
            for (int mi = 0; mi < 4; mi++)
#pragma unroll
                for (int ni = 0; ni < 4; ni++)
                    acc[mi][ni] = __builtin_amdgcn_mfma_f32_16x16x32_f16(
                        af[mi], bf[ni], acc[mi][ni], 0, 0, 0);
        }
        __syncthreads();
    }

    if (mat < 2) {
        const float* bias = (mat == 0) ? bq : bk;
        _Float16* Out = (mat == 0) ? Qcat : Kcat;
#pragma unroll
        for (int ni = 0; ni < 4; ni++) {
            int ch = bxn * 128 + wc * 64 + ni * 16 + (l & 15);
            float bb = bias[ch];
#pragma unroll
            for (int mi = 0; mi < 4; mi++)
#pragma unroll
                for (int rg = 0; rg < 4; rg++) {
                    int token = bym * 128 + wr * 64 + mi * 16 + (l >> 4) * 4 + rg;
                    float v = acc[mi][ni][rg] + bb;
                    _Float16 hi = (_Float16)v;
                    _Float16 lo = (_Float16)(v - (float)hi);
                    _Float16* p = Out + (size_t)token * KCAT + ch;
                    if (mat == 0) { p[0] = hi; p[256] = lo; p[512] = hi; }
                    else          { p[0] = hi; p[256] = hi; p[512] = lo; }
                }
        }
    } else {
#pragma unroll
        for (int mi = 0; mi < 4; mi++)
#pragma unroll
            for (int rg = 0; rg < 4; rg++) {
                int ch = bym * 128 + wr * 64 + mi * 16 + (l >> 4) * 4 + rg;
                float bb = bv[ch];
#pragma unroll
                for (int ni = 0; ni < 4; ni++) {
                    int col = bxn * 128 + wc * 64 + ni * 16 + (l & 15);
                    int b = col >> 12, n = col & 4095;
                    Vt[((size_t)((b << 8) + ch)) * NN + n] =
                        (_Float16)(acc[mi][ni][rg] + bb);
                }
            }
    }
}

// ---------- kernel 4: S = (Qcat @ Kcat^T) * SCALE via MFMA f16, 128x128 tile ----------
__global__ __launch_bounds__(256) void score_gemm(
        const _Float16* __restrict__ Qcat, const _Float16* __restrict__ Kcat,
        float* __restrict__ S) {
    __shared__ _Float16 As[128][72];
    __shared__ _Float16 Bs[128][72];

    const int t    = threadIdx.x;
    const int wave = t >> 6;
    const int l    = t & 63;
    const int wr   = wave >> 1;
    const int wc   = wave & 1;
    const int bxn  = blockIdx.x;
    const int bym  = blockIdx.y;
    const int b    = blockIdx.z;

    const int r = t >> 1;
    const int h = t & 1;

    const _Float16* Abase = Qcat + ((size_t)((b << 12) + bym * 128 + r)) * KCAT + h * 32;
    const _Float16* Bbase = Kcat + ((size_t)((b << 12) + bxn * 128 + r)) * KCAT + h * 32;

    floatx4 acc[4][4];
#pragma unroll
    for (int i = 0; i < 4; i++)
#pragma unroll
        for (int j = 0; j < 4; j++) acc[i][j] = (floatx4)0.0f;

    const int rowA = l & 15;
    const int koff = (l >> 4) * 8;

    for (int kc = 0; kc < KCAT; kc += 64) {
        const uint4* ap = (const uint4*)(Abase + kc);
        const uint4* bp = (const uint4*)(Bbase + kc);
        uint4 a0 = ap[0], a1 = ap[1], a2 = ap[2], a3 = ap[3];
        uint4 b0 = bp[0], b1 = bp[1], b2 = bp[2], b3 = bp[3];
        *(uint4*)&As[r][h * 32]      = a0;
        *(uint4*)&As[r][h * 32 + 8]  = a1;
        *(uint4*)&As[r][h * 32 + 16] = a2;
        *(uint4*)&As[r][h * 32 + 24] = a3;
        *(uint4*)&Bs[r][h * 32]      = b0;
        *(uint4*)&Bs[r][h * 32 + 8]  = b1;
        *(uint4*)&Bs[r][h * 32 + 16] = b2;
        *(uint4*)&Bs[r][h * 32 + 24] = b3;
        __syncthreads();
#pragma unroll
        for (int ks = 0; ks < 64; ks += 32) {
            half8 af[4], bf[4];
#pragma unroll
            for (int mi = 0; mi < 4; mi++)
                af[mi] = *(const half8*)&As[wr * 64 + mi * 16 + rowA][ks + koff];
#pragma unroll
            for (int ni = 0; ni < 4; ni++)
                bf[ni] = *(const half8*)&Bs[wc * 64 + ni * 16 + rowA][ks + koff];
#pragma unroll
            for (int mi = 0; mi < 4; mi++)
#pragma unroll
                for (int ni = 0; ni < 4; ni++)
                    acc[mi][ni] = __builtin_amdgcn_mfma_f32_16x16x32_f16(
                        af[mi], bf[ni], acc[mi][ni], 0, 0, 0);
        }
        __syncthreads();
    }

    float* Sb = S + ((size_t)b << 24);
#pragma unroll
    for (int mi = 0; mi < 4; mi++)
#pragma unroll
        for (int ni = 0; ni < 4; ni++) {
            int col = bxn * 128 + wc * 64 + ni * 16 + (l & 15);
#pragma unroll
            for (int rg = 0; rg < 4; rg++) {
                int row = bym * 128 + wr * 64 + mi * 16 + (l >> 4) * 4 + rg;
                Sb[((size_t)row << 12) + col] = acc[mi][ni][rg] * SCALE;
            }
        }
}

// ---------- kernel 5: per-row exact top-k + softmax -> dense fp16 P row ----------
__global__ __launch_bounds__(256) void select_scatter(
        const float* __restrict__ S, _Float16* __restrict__ P) {
    __shared__ unsigned hist[256];
    __shared__ unsigned scan[256];
    __shared__ unsigned candKey[NN];
    __shared__ unsigned wred[4];
    __shared__ float    wsum[4];
    __shared__ unsigned sh_d, sh_cntgt;
    __shared__ int      sh_ncand;

    const int t = threadIdx.x;
    const int l = t & 63;
    const int w = t >> 6;

    unsigned ukey[16];
    {
        const float*  Srow = S + ((size_t)blockIdx.x << 12);
        const float4* sp   = (const float4*)(Srow + t * 16);
#pragma unroll
        for (int jj = 0; jj < 4; jj++) {
            float4 v = sp[jj];
            ukey[jj * 4 + 0] = fkey(v.x); ukey[jj * 4 + 1] = fkey(v.y);
            ukey[jj * 4 + 2] = fkey(v.z); ukey[jj * 4 + 3] = fkey(v.w);
        }
    }

    unsigned lmax = 0u;
#pragma unroll
    for (int j = 0; j < 16; j++) lmax = max(lmax, ukey[j]);
#pragma unroll
    for (int off = 32; off > 0; off >>= 1) {
        unsigned o = __shfl_down(lmax, off);
        if (l + off < 64) lmax = max(lmax, o);
    }
    if (l == 0) wred[w] = lmax;

    hist[t] = 0u;
    if (t == 0) sh_ncand = 0;
    __syncthreads();
    const unsigned umax = max(max(wred[0], wred[1]), max(wred[2], wred[3]));

#pragma unroll
    for (int j = 0; j < 16; j++) atomicAdd(&hist[ukey[j] >> 24], 1u);
    __syncthreads();

    int rem = KK;
    unsigned prefix = 0u;

    auto find_digit = [&](int remv) {
        unsigned v = hist[t];
#pragma unroll
        for (int off = 1; off < 64; off <<= 1) {
            unsigned o = __shfl_down(v, off);
            if (l + off < 64) v += o;
        }
        if (l == 0) wred[w] = v;
        __syncthreads();
        unsigned add = 0u;
#pragma unroll
        for (int w2 = 0; w2 < 4; w2++) if (w2 > w) add += wred[w2];
        scan[t] = v + add;
        __syncthreads();
        unsigned sufd  = scan[t];
        unsigned sufd1 = (t < 255) ? scan[t + 1] : 0u;
        if (sufd >= (unsigned)remv && sufd1 < (unsigned)remv) {
            sh_d = (unsigned)t; sh_cntgt = sufd1;
        }
        __syncthreads();
    };

    find_digit(rem);
    const unsigned d1 = sh_d;
    rem -= (int)sh_cntgt;
    prefix = d1 << 24;

#pragma unroll
    for (int j = 0; j < 16; j++) {
        if ((ukey[j] >> 24) == d1) {
            int slot = atomicAdd(&sh_ncand, 1);
            candKey[slot] = ukey[j];
        }
    }
    __syncthreads();
    const int nc = sh_ncand;

    for (int pass = 1; pass < 4; pass++) {
        const int shift = 24 - 8 * pass;
        hist[t] = 0u;
        __syncthreads();
        for (int i = t; i < nc; i += 256) {
            unsigned u = candKey[i];
            if ((u >> (shift + 8)) == (prefix >> (shift + 8)))
                atomicAdd(&hist[(u >> shift) & 255u], 1u);
        }
        __syncthreads();
        find_digit(rem);
        prefix |= (sh_d << shift);
        rem -= (int)sh_cntgt;
    }
    const unsigned T = prefix;
    const int need = rem;

    int eqc = 0;
#pragma unroll
    for (int j = 0; j < 16; j++) if (ukey[j] == T) eqc++;
    int vinc = eqc;
#pragma unroll
    for (int off = 1; off < 64; off <<= 1) {
        int o = __shfl_up(vinc, off);
        if (l >= off) vinc += o;
    }
    if (l == 63) wred[w] = (unsigned)vinc;
    __syncthreads();
    int addlow = 0;
#pragma unroll
    for (int w2 = 0; w2 < 4; w2++) if (w2 < w) addlow += (int)wred[w2];
    const int eqexcl = vinc - eqc + addlow;

    const float mmax = keyToF(umax);
    float pv[16];
    float le = 0.f;
    int seen = 0;
#pragma unroll
    for (int j = 0; j < 16; j++) {
        unsigned u = ukey[j];
        bool sel = (u > T) || (u == T && (eqexcl + seen) < need);
        if (u == T) seen++;
        float e = 0.f;
        if (sel) { e = expf(keyToF(u) - mmax); le += e; }
        pv[j] = e;
    }

#pragma unroll
    for (int off = 32; off > 0; off >>= 1) {
        float o = __shfl_down(le, off);
        if (l + off < 64) le += o;
    }
    if (l == 0) wsum[w] = le;
    __syncthreads();
    const float inv = 1.0f / (wsum[0] + wsum[1] + wsum[2] + wsum[3]);

    half8 ra, rb;
#pragma unroll
    for (int j = 0; j < 8; j++) {
        ra[j] = (_Float16)(pv[j] * inv);
        rb[j] = (_Float16)(pv[j + 8] * inv);
    }
    _Float16* Pr = P + (size_t)blockIdx.x * PSTRIDE + t * 16;
    *(half8*)Pr       = ra;
    *(half8*)(Pr + 8) = rb;
}

// ---------- kernel 6: out[b][c][n] = sum_m Vt[c][m] * P[n][m] via MFMA f16 ----------
__global__ __launch_bounds__(256) void av_gemm(
        const _Float16* __restrict__ Vt, const _Float16* __restrict__ P,
        float* __restrict__ out) {
    __shared__ _Float16 As[64][72];
    __shared__ _Float16 Bs[64][72];

    const int t    = threadIdx.x;
    const int wave = t >> 6;
    const int l    = t & 63;
    const int wr   = wave >> 1;
    const int wc   = wave & 1;
    const int bxn  = blockIdx.x;
    const int byc  = blockIdx.y;
    const int b    = blockIdx.z;

    const int r = t >> 2;
    const int q = t & 3;

    const _Float16* Abase = Vt + ((size_t)((b << 8) + byc * 64 + r)) * NN + q * 16;
    const _Float16* Bbase = P + ((size_t)(b * NN + bxn * 64 + r)) * PSTRIDE + q * 16;

    floatx4 acc[2][2];
#pragma unroll
    for (int i = 0; i < 2; i++)
#pragma unroll
        for (int j = 0; j < 2; j++) acc[i][j] = (floatx4)0.0f;

    const int rowA = l & 15;
    const int koff = (l >> 4) * 8;

    for (int kc = 0; kc < NN; kc += 64) {
        const uint4* ap = (const uint4*)(Abase + kc);
        const uint4* bp = (const uint4*)(Bbase + kc);
        uint4 a0 = ap[0], a1 = ap[1];
        uint4 b0 = bp[0], b1 = bp[1];
        *(uint4*)&As[r][q * 16]     = a0;
        *(uint4*)&As[r][q * 16 + 8] = a1;
        *(uint4*)&Bs[r][q * 16]     = b0;
        *(uint4*)&Bs[r][q * 16 + 8] = b1;
        __syncthreads();
#pragma unroll
        for (int ks = 0; ks < 64; ks += 32) {
            half8 af[2], bf[2];
#pragma unroll
            for (int mi = 0; mi < 2; mi++)
                af[mi] = *(const half8*)&As[wr * 32 + mi * 16 + rowA][ks + koff];
#pragma unroll
            for (int ni = 0; ni < 2; ni++)
                bf[ni] = *(const half8*)&Bs[wc * 32 + ni * 16 + rowA][ks + koff];
#pragma unroll
            for (int mi = 0; mi < 2; mi++)
#pragma unroll
                for (int ni = 0; ni < 2; ni++)
                    acc[mi][ni] = __builtin_amdgcn_mfma_f32_16x16x32_f16(
                        af[mi], bf[ni], acc[mi][ni], 0, 0, 0);
        }
        __syncthreads();
    }

#pragma unroll
    for (int mi = 0; mi < 2; mi++)
#pragma unroll
        for (int ni = 0; ni < 2; ni++) {
            int col = bxn * 64 + wc * 32 + ni * 16 + (l & 15);
#pragma unroll
            for (int rg = 0; rg < 4; rg++) {
                int row = byc * 64 + wr * 32 + mi * 16 + (l >> 4) * 4 + rg;
                out[((size_t)((b << 8) + row) << 12) + col] = acc[mi][ni][rg];
            }
        }
}

extern "C" void kernel_launch(void* const* d_in, const int* in_sizes, int n_in,
                              void* d_out, int out_size, void* d_ws, size_t ws_size,
                              hipStream_t stream) {
    const float* x  = (const float*)d_in[0];
    const float* Wq = (const float*)d_in[1];
    const float* bq = (const float*)d_in[2];
    const float* Wk = (const float*)d_in[3];
    const float* bk = (const float*)d_in[4];
    const float* Wv = (const float*)d_in[5];
    const float* bv = (const float*)d_in[6];
    float* out = (float*)d_out;

    char* ws = (char*)d_ws;
    _Float16* Wcat = (_Float16*)ws;                            // 1.18 MB
    _Float16* Qcat = (_Float16*)(ws + 1179648);                // 12.6 MB
    _Float16* Kcat = (_Float16*)(ws + 1179648 + 12582912);     // 12.6 MB
    _Float16* Vt   = (_Float16*)(ws + 1179648 + 2 * 12582912); // 4 MB
    float*    S    = (float*)   (ws + 1179648 + 2 * 12582912 + 4194304); // 128 MB
    _Float16* xcat = (_Float16*)S;   // xcat dead before score_gemm writes S
    _Float16* P    = (_Float16*)S;   // P aliases S rows (proven safe)

    xpose_kernel<<<dim3(64, 4, BATCH), 256, 0, stream>>>(x, xcat);
    wcat_kernel<<<768, 256, 0, stream>>>(Wq, Wk, Wv, Wcat);
    proj_gemm<<<dim3(128, 1, 3), 256, 0, stream>>>(xcat, Wcat, bq, bk, bv,
                                                   Qcat, Kcat, Vt);
    score_gemm<<<dim3(32, 32, BATCH), 256, 0, stream>>>(Qcat, Kcat, S);
    select_scatter<<<BATCH * NN, 256, 0, stream>>>(S, P);
    av_gemm<<<dim3(64, 4, BATCH), 256, 0, stream>>>(Vt, P, out);
}